// Round 9
// baseline (952.012 us; speedup 1.0000x reference)
//
#include <hip/hip_runtime.h>
#include <hip/hip_bf16.h>
#include <cstdint>

#define HID 2048
#define ITR 1024
#define NE 8
#define NTOK 8192
#define BM 128
#define BN 128
#define BK 64
#define MAX_SLOTS 25600   // 16384 + 8*127 padding + 8192 shared, rounded

// ctrl layout (ints, buffer 8192 B). Counters padded 128 B apart (32 ints) to kill
// cross-XCD cache-line ping-pong (r6 lesson: packed counters cost 202 us in k_router).
#define C_CNT(e)  (32 * (e))          // histogram counts
#define C_FILL(e) (256 + 32 * (e))    // scatter fill cursors
#define C_PS      512                 // pstart[0..8]
#define C_TOTAL   521
#define C_ZEROB   4096                // byte offset: 256 B of zeros for pad-row gather

typedef __bf16 bf16;
typedef __bf16 bf16x4 __attribute__((ext_vector_type(4)));
typedef __bf16 bf16x8 __attribute__((ext_vector_type(8)));
typedef float f32x4 __attribute__((ext_vector_type(4)));

typedef const __attribute__((address_space(1))) void* gptr_t;
typedef __attribute__((address_space(3))) void* lptr_t;

__device__ __forceinline__ void gld_lds16(const void* g, void* l) {
  __builtin_amdgcn_global_load_lds((gptr_t)g, (lptr_t)l, 16, 0, 0);
}

// ---------------- fused front-end: weight transpose+convert AND router, one launch ----
// blocks [0, 13824): transpose job (27 z-slices x 512 tiles)
// blocks [13824, 15872): router job (2048 blocks x 4 tokens)
#define TCVT_BLOCKS 13824
__global__ void k_front(const float* __restrict__ x, const float* __restrict__ Wr,
                        bf16* __restrict__ Xbf, int* __restrict__ tki, float* __restrict__ tkw,
                        const float* __restrict__ Wg, const float* __restrict__ Wu,
                        const float* __restrict__ Wd,
                        const float* __restrict__ Wg_s, const float* __restrict__ Wu_s,
                        const float* __restrict__ Wd_s,
                        bf16* __restrict__ Wgt, bf16* __restrict__ Wut, bf16* __restrict__ Wdt) {
  __shared__ float tile[64][65];
  const int job = blockIdx.x;
  const int tid = threadIdx.x;

  if (job < TCVT_BLOCKS) {
    // ---- transpose+convert: [R][C] fp32 -> [C][R] bf16
    const int zz = job >> 9;            // 0..26
    const int bxy = job & 511;
    const int set = zz / 9, z = zz % 9;
    int R, C; const float* src; bf16* dst;
    if (set == 0)      { R = HID; C = ITR; src = (z < 8) ? Wg + (size_t)z * R * C : Wg_s; dst = Wgt + (size_t)z * R * C; }
    else if (set == 1) { R = HID; C = ITR; src = (z < 8) ? Wu + (size_t)z * R * C : Wu_s; dst = Wut + (size_t)z * R * C; }
    else               { R = ITR; C = HID; src = (z < 8) ? Wd + (size_t)z * R * C : Wd_s; dst = Wdt + (size_t)z * R * C; }
    const int nbx = C / 64;
    const int bx = bxy % nbx, by = bxy / nbx;
    const int c0 = bx * 64, r0 = by * 64;
    const int rr = tid >> 4, cc = (tid & 15) * 4;
#pragma unroll
    for (int j = 0; j < 4; ++j) {
      float4 v = *reinterpret_cast<const float4*>(&src[(size_t)(r0 + rr + j * 16) * C + c0 + cc]);
      tile[rr + j * 16][cc + 0] = v.x;
      tile[rr + j * 16][cc + 1] = v.y;
      tile[rr + j * 16][cc + 2] = v.z;
      tile[rr + j * 16][cc + 3] = v.w;
    }
    __syncthreads();
#pragma unroll
    for (int j = 0; j < 2; ++j) {
      int s = tid + j * 256;
      int oc = s >> 3, seg = s & 7;
      bf16x8 r;
#pragma unroll
      for (int i = 0; i < 8; ++i) r[i] = (bf16)tile[seg * 8 + i][oc];
      *reinterpret_cast<bf16x8*>(&dst[(size_t)(c0 + oc) * R + r0 + seg * 8]) = r;
    }
  } else {
    // ---- router (+ fused X fp32->bf16); NO atomics (r7 lesson)
    const int lane = tid & 63;
    const int t = (job - TCVT_BLOCKS) * 4 + (tid >> 6);
    const float4* xr = reinterpret_cast<const float4*>(x + (size_t)t * HID);
    bf16x4* xw = reinterpret_cast<bf16x4*>(Xbf + (size_t)t * HID);
    float acc[NE];
#pragma unroll
    for (int e = 0; e < NE; ++e) acc[e] = 0.f;
    for (int k = lane; k < HID / 4; k += 64) {
      float4 xv = xr[k];
      bf16x4 xb;
      xb[0] = (bf16)xv.x; xb[1] = (bf16)xv.y; xb[2] = (bf16)xv.z; xb[3] = (bf16)xv.w;
      xw[k] = xb;
#pragma unroll
      for (int e = 0; e < NE; ++e) {
        float4 wv = reinterpret_cast<const float4*>(Wr + (size_t)e * HID)[k];
        acc[e] += xv.x * wv.x + xv.y * wv.y + xv.z * wv.z + xv.w * wv.w;
      }
    }
#pragma unroll
    for (int off = 32; off; off >>= 1)
#pragma unroll
      for (int e = 0; e < NE; ++e) acc[e] += __shfl_xor(acc[e], off, 64);
    if (lane == 0) {
      int i0 = 0; float v0 = acc[0];
#pragma unroll
      for (int e = 1; e < NE; ++e) if (acc[e] > v0) { v0 = acc[e]; i0 = e; }
      int i1 = -1; float v1 = 0.f;
#pragma unroll
      for (int e = 0; e < NE; ++e) {
        if (e == i0) continue;
        if (i1 < 0 || acc[e] > v1) { v1 = acc[e]; i1 = e; }
      }
      float w1 = expf(v1 - v0);       // v0 >= v1
      float s = 1.f + w1;
      tki[t * 2] = i0; tki[t * 2 + 1] = i1;
      tkw[t * 2] = 1.f / s; tkw[t * 2 + 1] = w1 / s;
    }
  }
}

// ---------------- setup: atomic-free histogram + segment starts + pad fill ----------------
__global__ void k_setup(const int* __restrict__ tki, int* __restrict__ ctrl,
                        int* __restrict__ stok, float* __restrict__ sw) {
  const int tid = threadIdx.x;           // 1024 threads, 1 block
  const int lane = tid & 63, w = tid >> 6;
  int cnt[NE];
#pragma unroll
  for (int e = 0; e < NE; ++e) cnt[e] = 0;
  for (int i = tid; i < NTOK * 2; i += 1024) {
    const int e = tki[i];
#pragma unroll
    for (int ee = 0; ee < NE; ++ee) cnt[ee] += (e == ee) ? 1 : 0;
  }
#pragma unroll
  for (int off = 32; off; off >>= 1)
#pragma unroll
    for (int e = 0; e < NE; ++e) cnt[e] += __shfl_xor(cnt[e], off, 64);
  __shared__ int wcnt[16][NE];
  __shared__ int ps[9], cs[NE];
  if (lane == 0)
#pragma unroll
    for (int e = 0; e < NE; ++e) wcnt[w][e] = cnt[e];
  __syncthreads();
  if (tid == 0) {
    int run = 0;
    for (int e = 0; e < NE; ++e) {
      int c = 0;
      for (int ww = 0; ww < 16; ++ww) c += wcnt[ww][e];
      cs[e] = c;
      ps[e] = run;
      ctrl[C_CNT(e)] = c;
      ctrl[C_PS + e] = run;
      run += (c + 127) & ~127;
    }
    ps[8] = run;
    ctrl[C_PS + 8] = run;
    ctrl[C_TOTAL] = run + NTOK;
  }
  __syncthreads();
  for (int e = 0; e < NE; ++e) {
    const int c = cs[e];
    const int padded = (c + 127) & ~127;
    const int base = ps[e];
    for (int i = c + tid; i < padded; i += 1024) {
      stok[base + i] = -1; sw[base + i] = 0.f;
    }
  }
}

// ---------------- scatter: wave-aggregated placement (<=16 atomics/wave) ----------------
__global__ void k_scatter(const int* __restrict__ tki, const float* __restrict__ tkw,
                          int* __restrict__ ctrl, int* __restrict__ stok,
                          float* __restrict__ sw, int* __restrict__ tslot) {
  const int t = blockIdx.x * blockDim.x + threadIdx.x;
  const int lane = threadIdx.x & 63;
  const int sb = ctrl[C_PS + 8];
  stok[sb + t] = t; sw[sb + t] = 1.0f;
#pragma unroll
  for (int k = 0; k < 2; ++k) {
    const int e = tki[t * 2 + k];
    const float wgt = tkw[t * 2 + k];
#pragma unroll
    for (int ee = 0; ee < NE; ++ee) {
      const unsigned long long mask = __ballot(e == ee);
      if (e == ee) {
        const int leader = __ffsll(mask) - 1;
        const int rank = __popcll(mask & ((1ull << lane) - 1));
        int base = 0;
        if (lane == leader) base = atomicAdd(&ctrl[C_FILL(ee)], (int)__popcll(mask));
        base = __shfl(base, leader, 64);
        const int s = ctrl[C_PS + ee] + base + rank;
        stok[s] = t; sw[s] = wgt; tslot[t * 2 + k] = s;
      }
    }
  }
}

// ---------------- fused gate+up GEMM (r2 structure; 3 blocks/CU occupancy) ----------------
// LDS 50,176 B x 3 = 150.5 KB <= 160 KB; VGPR 108 << 170 cap at 3 waves/EU.
__launch_bounds__(256, 3)
__global__ void k_gateup(const bf16* __restrict__ Xbf,
                         const bf16* __restrict__ Wgt,
                         const bf16* __restrict__ Wut,
                         const int* __restrict__ stok_g,
                         const float* __restrict__ sw_g,
                         const int* __restrict__ ctrl,
                         bf16* __restrict__ hbuf) {
  __shared__ __align__(16) bf16 As[BM * BK];
  __shared__ __align__(16) bf16 Bgs[BN * BK];
  __shared__ __align__(16) bf16 Bus[BN * BK];
  __shared__ int stok[BM];
  __shared__ float swv[BM];

  const int total = ctrl[C_TOTAL];
  const int mt = blockIdx.y;
  const int sbase = mt * BM;
  if (sbase >= total) return;
  const int nt = blockIdx.x;

  int e;
  {
    const int shb = ctrl[C_PS + 8];
    if (sbase >= shb) e = 8;
    else { e = 0; while (e < 7 && ctrl[C_PS + e + 1] <= sbase) ++e; }
  }
  const bf16* __restrict__ Bg = Wgt + (size_t)e * ITR * HID;
  const bf16* __restrict__ Bu = Wut + (size_t)e * ITR * HID;
  const bf16* zerop = (const bf16*)((const char*)ctrl + C_ZEROB);

  const int tid = threadIdx.x;
  if (tid < BM) { stok[tid] = stok_g[sbase + tid]; swv[tid] = sw_g[sbase + tid]; }
  __syncthreads();

  const int lane = tid & 63;
  const int w = tid >> 6;
  const int wr = w >> 1, wc = w & 1;

  int rj[4], bj[4];
  const bf16* baseA[4];
  bool okA[4];
#pragma unroll
  for (int j = 0; j < 4; ++j) {
    rj[j] = (j * 4 + w) * 8 + (lane >> 3);
    bj[j] = (lane & 7) ^ (rj[j] & 7);          // pre-swizzled global source block
    int tk = stok[rj[j]];
    okA[j] = (tk >= 0);
    baseA[j] = Xbf + (size_t)(tk < 0 ? 0 : tk) * HID + bj[j] * 8;
  }

  f32x4 accg[4][4], accu[4][4];
#pragma unroll
  for (int m = 0; m < 4; ++m)
#pragma unroll
    for (int n = 0; n < 4; ++n) {
      accg[m][n] = f32x4{0.f, 0.f, 0.f, 0.f};
      accu[m][n] = f32x4{0.f, 0.f, 0.f, 0.f};
    }

  const int fr = lane & 15;
  const int kg = lane >> 4;
  const int rA0 = wr * 64 + fr;
  const int rB0 = wc * 64 + fr;
  const int sxz = fr & 7;

  for (int kt = 0; kt < HID / BK; ++kt) {       // 32 K-steps
    const int kofs = kt * BK;
    __syncthreads();
#pragma unroll
    for (int j = 0; j < 4; ++j) {
      const bf16* sA = okA[j] ? (baseA[j] + kofs) : zerop;
      gld_lds16(sA, (char*)As + (j * 4 + w) * 1024);
      const size_t bo = (size_t)(nt * BN + rj[j]) * HID + kofs + bj[j] * 8;
      gld_lds16(Bg + bo, (char*)Bgs + (j * 4 + w) * 1024);
      gld_lds16(Bu + bo, (char*)Bus + (j * 4 + w) * 1024);
    }
    __syncthreads();
#pragma unroll
    for (int kc = 0; kc < 2; ++kc) {
      const int pa = ((kg + 4 * kc) ^ sxz) * 8;
      bf16x8 av[4], gv[4], uv[4];
#pragma unroll
      for (int m = 0; m < 4; ++m) {
        av[m] = *reinterpret_cast<const bf16x8*>(As + (rA0 + m * 16) * BK + pa);
        gv[m] = *reinterpret_cast<const bf16x8*>(Bgs + (rB0 + m * 16) * BK + pa);
        uv[m] = *reinterpret_cast<const bf16x8*>(Bus + (rB0 + m * 16) * BK + pa);
      }
#pragma unroll
      for (int m = 0; m < 4; ++m)
#pragma unroll
        for (int n = 0; n < 4; ++n) {
          accg[m][n] = __builtin_amdgcn_mfma_f32_16x16x32_bf16(av[m], gv[n], accg[m][n], 0, 0, 0);
          accu[m][n] = __builtin_amdgcn_mfma_f32_16x16x32_bf16(av[m], uv[n], accu[m][n], 0, 0, 0);
        }
    }
  }

#pragma unroll
  for (int m = 0; m < 4; ++m) {
    const int row = wr * 64 + m * 16 + kg * 4;
#pragma unroll
    for (int n = 0; n < 4; ++n) {
      const int col = nt * BN + wc * 64 + n * 16 + fr;
#pragma unroll
      for (int r = 0; r < 4; ++r) {
        float g = accg[m][n][r];
        float u = accu[m][n][r];
        float val = swv[row + r] * (g / (1.f + expf(-g))) * u;
        hbuf[(size_t)(sbase + row + r) * ITR + col] = (bf16)val;
      }
    }
  }
}

// ---------------- down GEMM -> per-slot bf16 rows (r2 structure; 4 blocks/CU) ----------------
// LDS 33,280 B x 4 = 133 KB <= 160 KB; VGPR cap 128 at 4 waves/EU.
__launch_bounds__(256, 4)
__global__ void k_down(const bf16* __restrict__ hbuf,
                       const bf16* __restrict__ Wdt,
                       const int* __restrict__ stok_g,
                       const int* __restrict__ ctrl,
                       bf16* __restrict__ dbuf) {
  __shared__ __align__(16) bf16 As[BM * BK];
  __shared__ __align__(16) bf16 Bs[BN * BK];
  __shared__ int stok[BM];

  const int total = ctrl[C_TOTAL];
  const int mt = blockIdx.y;
  const int sbase = mt * BM;
  if (sbase >= total) return;
  const int nt = blockIdx.x;

  int e;
  {
    const int shb = ctrl[C_PS + 8];
    if (sbase >= shb) e = 8;
    else { e = 0; while (e < 7 && ctrl[C_PS + e + 1] <= sbase) ++e; }
  }
  const bf16* __restrict__ Bd = Wdt + (size_t)e * HID * ITR;

  const int tid = threadIdx.x;
  if (tid < BM) stok[tid] = stok_g[sbase + tid];
  __syncthreads();

  const int lane = tid & 63;
  const int w = tid >> 6;
  const int wr = w >> 1, wc = w & 1;

  int rj[4], bj[4];
#pragma unroll
  for (int j = 0; j < 4; ++j) {
    rj[j] = (j * 4 + w) * 8 + (lane >> 3);
    bj[j] = (lane & 7) ^ (rj[j] & 7);
  }

  f32x4 acc[4][4];
#pragma unroll
  for (int m = 0; m < 4; ++m)
#pragma unroll
    for (int n = 0; n < 4; ++n) acc[m][n] = f32x4{0.f, 0.f, 0.f, 0.f};

  const int fr = lane & 15;
  const int kg = lane >> 4;
  const int rA0 = wr * 64 + fr;
  const int rB0 = wc * 64 + fr;
  const int sxz = fr & 7;

  for (int kt = 0; kt < ITR / BK; ++kt) {       // 16 K-steps
    const int kofs = kt * BK;
    __syncthreads();
#pragma unroll
    for (int j = 0; j < 4; ++j) {
      gld_lds16(hbuf + (size_t)(sbase + rj[j]) * ITR + kofs + bj[j] * 8,
                (char*)As + (j * 4 + w) * 1024);
      gld_lds16(Bd + (size_t)(nt * BN + rj[j]) * ITR + kofs + bj[j] * 8,
                (char*)Bs + (j * 4 + w) * 1024);
    }
    __syncthreads();
#pragma unroll
    for (int kc = 0; kc < 2; ++kc) {
      const int pa = ((kg + 4 * kc) ^ sxz) * 8;
      bf16x8 av[4], bv[4];
#pragma unroll
      for (int m = 0; m < 4; ++m) {
        av[m] = *reinterpret_cast<const bf16x8*>(As + (rA0 + m * 16) * BK + pa);
        bv[m] = *reinterpret_cast<const bf16x8*>(Bs + (rB0 + m * 16) * BK + pa);
      }
#pragma unroll
      for (int m = 0; m < 4; ++m)
#pragma unroll
        for (int n = 0; n < 4; ++n)
          acc[m][n] = __builtin_amdgcn_mfma_f32_16x16x32_bf16(av[m], bv[n], acc[m][n], 0, 0, 0);
    }
  }

#pragma unroll
  for (int m = 0; m < 4; ++m) {
    const int row = wr * 64 + m * 16 + kg * 4;
#pragma unroll
    for (int r = 0; r < 4; ++r) {
      if (stok[row + r] < 0) continue;          // pad slot: never read
#pragma unroll
      for (int n = 0; n < 4; ++n) {
        const int col = nt * BN + wc * 64 + n * 16 + fr;
        dbuf[(size_t)(sbase + row + r) * HID + col] = (bf16)acc[m][n][r];
      }
    }
  }
}

// ---------------- combine: out[t] = dbuf[shared(t)] + dbuf[s0] + dbuf[s1] ----------------
__global__ void k_combine(const bf16* __restrict__ dbuf, const int* __restrict__ tslot,
                          const int* __restrict__ ctrl, float* __restrict__ out) {
  const int t = blockIdx.x;
  const int sb = ctrl[C_PS + 8];
  const int s0 = tslot[t * 2], s1 = tslot[t * 2 + 1];
  const int c = threadIdx.x * 8;
  bf16x8 a = *reinterpret_cast<const bf16x8*>(&dbuf[(size_t)(sb + t) * HID + c]);
  bf16x8 b = *reinterpret_cast<const bf16x8*>(&dbuf[(size_t)s0 * HID + c]);
  bf16x8 d = *reinterpret_cast<const bf16x8*>(&dbuf[(size_t)s1 * HID + c]);
  float r[8];
#pragma unroll
  for (int i = 0; i < 8; ++i) r[i] = (float)a[i] + (float)b[i] + (float)d[i];
  float4* o = reinterpret_cast<float4*>(&out[(size_t)t * HID + c]);
  o[0] = float4{r[0], r[1], r[2], r[3]};
  o[1] = float4{r[4], r[5], r[6], r[7]};
}

// ---------------- launch ----------------
extern "C" void kernel_launch(void* const* d_in, const int* in_sizes, int n_in,
                              void* d_out, int out_size, void* d_ws, size_t ws_size,
                              hipStream_t stream) {
  const float* x    = (const float*)d_in[0];
  const float* Wr   = (const float*)d_in[1];
  const float* Wg   = (const float*)d_in[2];
  const float* Wu   = (const float*)d_in[3];
  const float* Wd   = (const float*)d_in[4];
  const float* Wg_s = (const float*)d_in[5];
  const float* Wu_s = (const float*)d_in[6];
  const float* Wd_s = (const float*)d_in[7];
  float* out = (float*)d_out;

  char* ws = (char*)d_ws;
  size_t off = 0;
  auto alloc = [&](size_t b) { char* p = ws + off; off += (b + 255) & ~(size_t)255; return p; };
  bf16* Xbf  = (bf16*)alloc((size_t)NTOK * HID * 2);        // 33,554,432
  bf16* Wgt  = (bf16*)alloc((size_t)9 * ITR * HID * 2);     // 37,748,736
  bf16* Wut  = (bf16*)alloc((size_t)9 * ITR * HID * 2);     // 37,748,736
  bf16* Wdt  = (bf16*)alloc((size_t)9 * HID * ITR * 2);     // 37,748,736
  bf16* hbuf = (bf16*)alloc((size_t)MAX_SLOTS * ITR * 2);   // 52,428,800
  int*   stok = (int*)alloc((size_t)MAX_SLOTS * 4);
  float* sw   = (float*)alloc((size_t)MAX_SLOTS * 4);
  int*   tki  = (int*)alloc((size_t)NTOK * 2 * 4);
  float* tkw  = (float*)alloc((size_t)NTOK * 2 * 4);
  int*   tslot= (int*)alloc((size_t)NTOK * 2 * 4);
  int*   ctrl = (int*)alloc(8192);

  // dbuf (25600*2048*2 = 104,857,600 B) aliases [Xbf..Wut) (109,051,904 B): all three
  // are dead once k_gateup finishes; k_down/k_combine are dbuf's only users.
  bf16* dbuf = (bf16*)Xbf;

  hipMemsetAsync(ctrl, 0, 8192, stream);

  k_front<<<dim3(TCVT_BLOCKS + NTOK / 4), dim3(256), 0, stream>>>(
      x, Wr, Xbf, tki, tkw, Wg, Wu, Wd, Wg_s, Wu_s, Wd_s, Wgt, Wut, Wdt);
  k_setup<<<dim3(1), dim3(1024), 0, stream>>>(tki, ctrl, stok, sw);
  k_scatter<<<dim3(NTOK / 256), dim3(256), 0, stream>>>(tki, tkw, ctrl, stok, sw, tslot);
  k_gateup<<<dim3(ITR / BN, MAX_SLOTS / BM), dim3(256), 0, stream>>>(Xbf, Wgt, Wut, stok, sw, ctrl, hbuf);
  k_down<<<dim3(HID / BN, MAX_SLOTS / BM), dim3(256), 0, stream>>>(hbuf, Wdt, stok, ctrl, dbuf);
  k_combine<<<dim3(NTOK), dim3(256), 0, stream>>>(dbuf, tslot, ctrl, out);
}

// Round 10
// 476.876 us; speedup vs baseline: 1.9964x; 1.9964x over previous
//
#include <hip/hip_runtime.h>
#include <hip/hip_bf16.h>
#include <cstdint>

#define HID 2048
#define ITR 1024
#define NE 8
#define NTOK 8192
#define BM 128
#define BN 128
#define BK 64
#define MAX_SLOTS 25600   // 16384 + 8*127 padding + 8192 shared, rounded

// ctrl layout (ints, buffer 8192 B). Counters padded 128 B apart (32 ints) to kill
// cross-XCD cache-line ping-pong (r6 lesson: packed counters cost 202 us in k_router).
#define C_CNT(e)  (32 * (e))          // histogram counts
#define C_FILL(e) (256 + 32 * (e))    // scatter fill cursors
#define C_PS      512                 // pstart[0..8]
#define C_TOTAL   521
#define C_ZEROB   4096                // byte offset: 256 B of zeros for pad-row gather

typedef __bf16 bf16;
typedef __bf16 bf16x4 __attribute__((ext_vector_type(4)));
typedef __bf16 bf16x8 __attribute__((ext_vector_type(8)));
typedef float f32x4 __attribute__((ext_vector_type(4)));

typedef const __attribute__((address_space(1))) void* gptr_t;
typedef __attribute__((address_space(3))) void* lptr_t;

__device__ __forceinline__ void gld_lds16(const void* g, void* l) {
  __builtin_amdgcn_global_load_lds((gptr_t)g, (lptr_t)l, 16, 0, 0);
}

// ---------------- fused front-end: weight transpose+convert AND router, one launch ----
// blocks [0, 13824): transpose job (27 z-slices x 512 tiles)
// blocks [13824, 15872): router job (2048 blocks x 4 tokens)
#define TCVT_BLOCKS 13824
__global__ void k_front(const float* __restrict__ x, const float* __restrict__ Wr,
                        bf16* __restrict__ Xbf, int* __restrict__ tki, float* __restrict__ tkw,
                        const float* __restrict__ Wg, const float* __restrict__ Wu,
                        const float* __restrict__ Wd,
                        const float* __restrict__ Wg_s, const float* __restrict__ Wu_s,
                        const float* __restrict__ Wd_s,
                        bf16* __restrict__ Wgt, bf16* __restrict__ Wut, bf16* __restrict__ Wdt) {
  __shared__ float tile[64][65];
  const int job = blockIdx.x;
  const int tid = threadIdx.x;

  if (job < TCVT_BLOCKS) {
    // ---- transpose+convert: [R][C] fp32 -> [C][R] bf16
    const int zz = job >> 9;            // 0..26
    const int bxy = job & 511;
    const int set = zz / 9, z = zz % 9;
    int R, C; const float* src; bf16* dst;
    if (set == 0)      { R = HID; C = ITR; src = (z < 8) ? Wg + (size_t)z * R * C : Wg_s; dst = Wgt + (size_t)z * R * C; }
    else if (set == 1) { R = HID; C = ITR; src = (z < 8) ? Wu + (size_t)z * R * C : Wu_s; dst = Wut + (size_t)z * R * C; }
    else               { R = ITR; C = HID; src = (z < 8) ? Wd + (size_t)z * R * C : Wd_s; dst = Wdt + (size_t)z * R * C; }
    const int nbx = C / 64;
    const int bx = bxy % nbx, by = bxy / nbx;
    const int c0 = bx * 64, r0 = by * 64;
    const int rr = tid >> 4, cc = (tid & 15) * 4;
#pragma unroll
    for (int j = 0; j < 4; ++j) {
      float4 v = *reinterpret_cast<const float4*>(&src[(size_t)(r0 + rr + j * 16) * C + c0 + cc]);
      tile[rr + j * 16][cc + 0] = v.x;
      tile[rr + j * 16][cc + 1] = v.y;
      tile[rr + j * 16][cc + 2] = v.z;
      tile[rr + j * 16][cc + 3] = v.w;
    }
    __syncthreads();
#pragma unroll
    for (int j = 0; j < 2; ++j) {
      int s = tid + j * 256;
      int oc = s >> 3, seg = s & 7;
      bf16x8 r;
#pragma unroll
      for (int i = 0; i < 8; ++i) r[i] = (bf16)tile[seg * 8 + i][oc];
      *reinterpret_cast<bf16x8*>(&dst[(size_t)(c0 + oc) * R + r0 + seg * 8]) = r;
    }
  } else {
    // ---- router (+ fused X fp32->bf16); NO atomics (r7 lesson)
    const int lane = tid & 63;
    const int t = (job - TCVT_BLOCKS) * 4 + (tid >> 6);
    const float4* xr = reinterpret_cast<const float4*>(x + (size_t)t * HID);
    bf16x4* xw = reinterpret_cast<bf16x4*>(Xbf + (size_t)t * HID);
    float acc[NE];
#pragma unroll
    for (int e = 0; e < NE; ++e) acc[e] = 0.f;
    for (int k = lane; k < HID / 4; k += 64) {
      float4 xv = xr[k];
      bf16x4 xb;
      xb[0] = (bf16)xv.x; xb[1] = (bf16)xv.y; xb[2] = (bf16)xv.z; xb[3] = (bf16)xv.w;
      xw[k] = xb;
#pragma unroll
      for (int e = 0; e < NE; ++e) {
        float4 wv = reinterpret_cast<const float4*>(Wr + (size_t)e * HID)[k];
        acc[e] += xv.x * wv.x + xv.y * wv.y + xv.z * wv.z + xv.w * wv.w;
      }
    }
#pragma unroll
    for (int off = 32; off; off >>= 1)
#pragma unroll
      for (int e = 0; e < NE; ++e) acc[e] += __shfl_xor(acc[e], off, 64);
    if (lane == 0) {
      int i0 = 0; float v0 = acc[0];
#pragma unroll
      for (int e = 1; e < NE; ++e) if (acc[e] > v0) { v0 = acc[e]; i0 = e; }
      int i1 = -1; float v1 = 0.f;
#pragma unroll
      for (int e = 0; e < NE; ++e) {
        if (e == i0) continue;
        if (i1 < 0 || acc[e] > v1) { v1 = acc[e]; i1 = e; }
      }
      float w1 = expf(v1 - v0);       // v0 >= v1
      float s = 1.f + w1;
      tki[t * 2] = i0; tki[t * 2 + 1] = i1;
      tkw[t * 2] = 1.f / s; tkw[t * 2 + 1] = w1 / s;
    }
  }
}

// ---------------- setup: atomic-free histogram + segment starts + pad fill ----------------
__global__ void k_setup(const int* __restrict__ tki, int* __restrict__ ctrl,
                        int* __restrict__ stok, float* __restrict__ sw) {
  const int tid = threadIdx.x;           // 1024 threads, 1 block
  const int lane = tid & 63, w = tid >> 6;
  int cnt[NE];
#pragma unroll
  for (int e = 0; e < NE; ++e) cnt[e] = 0;
  for (int i = tid; i < NTOK * 2; i += 1024) {
    const int e = tki[i];
#pragma unroll
    for (int ee = 0; ee < NE; ++ee) cnt[ee] += (e == ee) ? 1 : 0;
  }
#pragma unroll
  for (int off = 32; off; off >>= 1)
#pragma unroll
    for (int e = 0; e < NE; ++e) cnt[e] += __shfl_xor(cnt[e], off, 64);
  __shared__ int wcnt[16][NE];
  __shared__ int ps[9], cs[NE];
  if (lane == 0)
#pragma unroll
    for (int e = 0; e < NE; ++e) wcnt[w][e] = cnt[e];
  __syncthreads();
  if (tid == 0) {
    int run = 0;
    for (int e = 0; e < NE; ++e) {
      int c = 0;
      for (int ww = 0; ww < 16; ++ww) c += wcnt[ww][e];
      cs[e] = c;
      ps[e] = run;
      ctrl[C_CNT(e)] = c;
      ctrl[C_PS + e] = run;
      run += (c + 127) & ~127;
    }
    ps[8] = run;
    ctrl[C_PS + 8] = run;
    ctrl[C_TOTAL] = run + NTOK;
  }
  __syncthreads();
  for (int e = 0; e < NE; ++e) {
    const int c = cs[e];
    const int padded = (c + 127) & ~127;
    const int base = ps[e];
    for (int i = c + tid; i < padded; i += 1024) {
      stok[base + i] = -1; sw[base + i] = 0.f;
    }
  }
}

// ---------------- scatter: wave-aggregated placement (<=16 atomics/wave) ----------------
__global__ void k_scatter(const int* __restrict__ tki, const float* __restrict__ tkw,
                          int* __restrict__ ctrl, int* __restrict__ stok,
                          float* __restrict__ sw, int* __restrict__ tslot) {
  const int t = blockIdx.x * blockDim.x + threadIdx.x;
  const int lane = threadIdx.x & 63;
  const int sb = ctrl[C_PS + 8];
  stok[sb + t] = t; sw[sb + t] = 1.0f;
#pragma unroll
  for (int k = 0; k < 2; ++k) {
    const int e = tki[t * 2 + k];
    const float wgt = tkw[t * 2 + k];
#pragma unroll
    for (int ee = 0; ee < NE; ++ee) {
      const unsigned long long mask = __ballot(e == ee);
      if (e == ee) {
        const int leader = __ffsll(mask) - 1;
        const int rank = __popcll(mask & ((1ull << lane) - 1));
        int base = 0;
        if (lane == leader) base = atomicAdd(&ctrl[C_FILL(ee)], (int)__popcll(mask));
        base = __shfl(base, leader, 64);
        const int s = ctrl[C_PS + ee] + base + rank;
        stok[s] = t; sw[s] = wgt; tslot[t * 2 + k] = s;
      }
    }
  }
}

// ---------------- fused gate+up GEMM (r2-verified structure) ----------------
// __launch_bounds__(256,2) is CORRECT and structural (r9 lesson): per-wave register
// budget on gfx950 is UNIFIED VGPR+AGPR; this kernel uses ~108 VGPR + 128 AGPR
// (accg+accu) = 236/wave -> 512/236 = 2 waves/SIMD. Requesting 3 waves/EU caps the
// allocator at 170 and forces scratch spills (r9: WRITE_SIZE 50->500 MB, dur 264->750).
__launch_bounds__(256, 2)
__global__ void k_gateup(const bf16* __restrict__ Xbf,
                         const bf16* __restrict__ Wgt,
                         const bf16* __restrict__ Wut,
                         const int* __restrict__ stok_g,
                         const float* __restrict__ sw_g,
                         const int* __restrict__ ctrl,
                         bf16* __restrict__ hbuf) {
  __shared__ __align__(16) bf16 As[BM * BK];
  __shared__ __align__(16) bf16 Bgs[BN * BK];
  __shared__ __align__(16) bf16 Bus[BN * BK];
  __shared__ int stok[BM];
  __shared__ float swv[BM];

  const int total = ctrl[C_TOTAL];
  const int mt = blockIdx.y;
  const int sbase = mt * BM;
  if (sbase >= total) return;
  const int nt = blockIdx.x;

  int e;
  {
    const int shb = ctrl[C_PS + 8];
    if (sbase >= shb) e = 8;
    else { e = 0; while (e < 7 && ctrl[C_PS + e + 1] <= sbase) ++e; }
  }
  const bf16* __restrict__ Bg = Wgt + (size_t)e * ITR * HID;
  const bf16* __restrict__ Bu = Wut + (size_t)e * ITR * HID;
  const bf16* zerop = (const bf16*)((const char*)ctrl + C_ZEROB);

  const int tid = threadIdx.x;
  if (tid < BM) { stok[tid] = stok_g[sbase + tid]; swv[tid] = sw_g[sbase + tid]; }
  __syncthreads();

  const int lane = tid & 63;
  const int w = tid >> 6;
  const int wr = w >> 1, wc = w & 1;

  int rj[4], bj[4];
  const bf16* baseA[4];
  bool okA[4];
#pragma unroll
  for (int j = 0; j < 4; ++j) {
    rj[j] = (j * 4 + w) * 8 + (lane >> 3);
    bj[j] = (lane & 7) ^ (rj[j] & 7);          // pre-swizzled global source block
    int tk = stok[rj[j]];
    okA[j] = (tk >= 0);
    baseA[j] = Xbf + (size_t)(tk < 0 ? 0 : tk) * HID + bj[j] * 8;
  }

  f32x4 accg[4][4], accu[4][4];
#pragma unroll
  for (int m = 0; m < 4; ++m)
#pragma unroll
    for (int n = 0; n < 4; ++n) {
      accg[m][n] = f32x4{0.f, 0.f, 0.f, 0.f};
      accu[m][n] = f32x4{0.f, 0.f, 0.f, 0.f};
    }

  const int fr = lane & 15;
  const int kg = lane >> 4;
  const int rA0 = wr * 64 + fr;
  const int rB0 = wc * 64 + fr;
  const int sxz = fr & 7;

  for (int kt = 0; kt < HID / BK; ++kt) {       // 32 K-steps
    const int kofs = kt * BK;
    __syncthreads();
#pragma unroll
    for (int j = 0; j < 4; ++j) {
      const bf16* sA = okA[j] ? (baseA[j] + kofs) : zerop;
      gld_lds16(sA, (char*)As + (j * 4 + w) * 1024);
      const size_t bo = (size_t)(nt * BN + rj[j]) * HID + kofs + bj[j] * 8;
      gld_lds16(Bg + bo, (char*)Bgs + (j * 4 + w) * 1024);
      gld_lds16(Bu + bo, (char*)Bus + (j * 4 + w) * 1024);
    }
    __syncthreads();
#pragma unroll
    for (int kc = 0; kc < 2; ++kc) {
      const int pa = ((kg + 4 * kc) ^ sxz) * 8;
      bf16x8 av[4], gv[4], uv[4];
#pragma unroll
      for (int m = 0; m < 4; ++m) {
        av[m] = *reinterpret_cast<const bf16x8*>(As + (rA0 + m * 16) * BK + pa);
        gv[m] = *reinterpret_cast<const bf16x8*>(Bgs + (rB0 + m * 16) * BK + pa);
        uv[m] = *reinterpret_cast<const bf16x8*>(Bus + (rB0 + m * 16) * BK + pa);
      }
#pragma unroll
      for (int m = 0; m < 4; ++m)
#pragma unroll
        for (int n = 0; n < 4; ++n) {
          accg[m][n] = __builtin_amdgcn_mfma_f32_16x16x32_bf16(av[m], gv[n], accg[m][n], 0, 0, 0);
          accu[m][n] = __builtin_amdgcn_mfma_f32_16x16x32_bf16(av[m], uv[n], accu[m][n], 0, 0, 0);
        }
    }
  }

#pragma unroll
  for (int m = 0; m < 4; ++m) {
    const int row = wr * 64 + m * 16 + kg * 4;
#pragma unroll
    for (int n = 0; n < 4; ++n) {
      const int col = nt * BN + wc * 64 + n * 16 + fr;
#pragma unroll
      for (int r = 0; r < 4; ++r) {
        float g = accg[m][n][r];
        float u = accu[m][n][r];
        float val = swv[row + r] * (g / (1.f + expf(-g))) * u;
        hbuf[(size_t)(sbase + row + r) * ITR + col] = (bf16)val;
      }
    }
  }
}

// ---------------- down GEMM -> per-slot bf16 rows (r2-verified structure) ----------------
// (256,2): 64 AGPR acc + ~100 VGPR > 128-cap of 4 waves/EU -> (256,4) spills (r9).
__launch_bounds__(256, 2)
__global__ void k_down(const bf16* __restrict__ hbuf,
                       const bf16* __restrict__ Wdt,
                       const int* __restrict__ stok_g,
                       const int* __restrict__ ctrl,
                       bf16* __restrict__ dbuf) {
  __shared__ __align__(16) bf16 As[BM * BK];
  __shared__ __align__(16) bf16 Bs[BN * BK];
  __shared__ int stok[BM];

  const int total = ctrl[C_TOTAL];
  const int mt = blockIdx.y;
  const int sbase = mt * BM;
  if (sbase >= total) return;
  const int nt = blockIdx.x;

  int e;
  {
    const int shb = ctrl[C_PS + 8];
    if (sbase >= shb) e = 8;
    else { e = 0; while (e < 7 && ctrl[C_PS + e + 1] <= sbase) ++e; }
  }
  const bf16* __restrict__ Bd = Wdt + (size_t)e * HID * ITR;

  const int tid = threadIdx.x;
  if (tid < BM) stok[tid] = stok_g[sbase + tid];
  __syncthreads();

  const int lane = tid & 63;
  const int w = tid >> 6;
  const int wr = w >> 1, wc = w & 1;

  int rj[4], bj[4];
#pragma unroll
  for (int j = 0; j < 4; ++j) {
    rj[j] = (j * 4 + w) * 8 + (lane >> 3);
    bj[j] = (lane & 7) ^ (rj[j] & 7);
  }

  f32x4 acc[4][4];
#pragma unroll
  for (int m = 0; m < 4; ++m)
#pragma unroll
    for (int n = 0; n < 4; ++n) acc[m][n] = f32x4{0.f, 0.f, 0.f, 0.f};

  const int fr = lane & 15;
  const int kg = lane >> 4;
  const int rA0 = wr * 64 + fr;
  const int rB0 = wc * 64 + fr;
  const int sxz = fr & 7;

  for (int kt = 0; kt < ITR / BK; ++kt) {       // 16 K-steps
    const int kofs = kt * BK;
    __syncthreads();
#pragma unroll
    for (int j = 0; j < 4; ++j) {
      gld_lds16(hbuf + (size_t)(sbase + rj[j]) * ITR + kofs + bj[j] * 8,
                (char*)As + (j * 4 + w) * 1024);
      gld_lds16(Bd + (size_t)(nt * BN + rj[j]) * ITR + kofs + bj[j] * 8,
                (char*)Bs + (j * 4 + w) * 1024);
    }
    __syncthreads();
#pragma unroll
    for (int kc = 0; kc < 2; ++kc) {
      const int pa = ((kg + 4 * kc) ^ sxz) * 8;
      bf16x8 av[4], bv[4];
#pragma unroll
      for (int m = 0; m < 4; ++m) {
        av[m] = *reinterpret_cast<const bf16x8*>(As + (rA0 + m * 16) * BK + pa);
        bv[m] = *reinterpret_cast<const bf16x8*>(Bs + (rB0 + m * 16) * BK + pa);
      }
#pragma unroll
      for (int m = 0; m < 4; ++m)
#pragma unroll
        for (int n = 0; n < 4; ++n)
          acc[m][n] = __builtin_amdgcn_mfma_f32_16x16x32_bf16(av[m], bv[n], acc[m][n], 0, 0, 0);
    }
  }

#pragma unroll
  for (int m = 0; m < 4; ++m) {
    const int row = wr * 64 + m * 16 + kg * 4;
#pragma unroll
    for (int r = 0; r < 4; ++r) {
      if (stok[row + r] < 0) continue;          // pad slot: never read
#pragma unroll
      for (int n = 0; n < 4; ++n) {
        const int col = nt * BN + wc * 64 + n * 16 + fr;
        dbuf[(size_t)(sbase + row + r) * HID + col] = (bf16)acc[m][n][r];
      }
    }
  }
}

// ---------------- combine: out[t] = dbuf[shared(t)] + dbuf[s0] + dbuf[s1] ----------------
__global__ void k_combine(const bf16* __restrict__ dbuf, const int* __restrict__ tslot,
                          const int* __restrict__ ctrl, float* __restrict__ out) {
  const int t = blockIdx.x;
  const int sb = ctrl[C_PS + 8];
  const int s0 = tslot[t * 2], s1 = tslot[t * 2 + 1];
  const int c = threadIdx.x * 8;
  bf16x8 a = *reinterpret_cast<const bf16x8*>(&dbuf[(size_t)(sb + t) * HID + c]);
  bf16x8 b = *reinterpret_cast<const bf16x8*>(&dbuf[(size_t)s0 * HID + c]);
  bf16x8 d = *reinterpret_cast<const bf16x8*>(&dbuf[(size_t)s1 * HID + c]);
  float r[8];
#pragma unroll
  for (int i = 0; i < 8; ++i) r[i] = (float)a[i] + (float)b[i] + (float)d[i];
  float4* o = reinterpret_cast<float4*>(&out[(size_t)t * HID + c]);
  o[0] = float4{r[0], r[1], r[2], r[3]};
  o[1] = float4{r[4], r[5], r[6], r[7]};
}

// ---------------- launch ----------------
extern "C" void kernel_launch(void* const* d_in, const int* in_sizes, int n_in,
                              void* d_out, int out_size, void* d_ws, size_t ws_size,
                              hipStream_t stream) {
  const float* x    = (const float*)d_in[0];
  const float* Wr   = (const float*)d_in[1];
  const float* Wg   = (const float*)d_in[2];
  const float* Wu   = (const float*)d_in[3];
  const float* Wd   = (const float*)d_in[4];
  const float* Wg_s = (const float*)d_in[5];
  const float* Wu_s = (const float*)d_in[6];
  const float* Wd_s = (const float*)d_in[7];
  float* out = (float*)d_out;

  char* ws = (char*)d_ws;
  size_t off = 0;
  auto alloc = [&](size_t b) { char* p = ws + off; off += (b + 255) & ~(size_t)255; return p; };
  bf16* Xbf  = (bf16*)alloc((size_t)NTOK * HID * 2);        // 33,554,432
  bf16* Wgt  = (bf16*)alloc((size_t)9 * ITR * HID * 2);     // 37,748,736
  bf16* Wut  = (bf16*)alloc((size_t)9 * ITR * HID * 2);     // 37,748,736
  bf16* Wdt  = (bf16*)alloc((size_t)9 * HID * ITR * 2);     // 37,748,736
  bf16* hbuf = (bf16*)alloc((size_t)MAX_SLOTS * ITR * 2);   // 52,428,800
  int*   stok = (int*)alloc((size_t)MAX_SLOTS * 4);
  float* sw   = (float*)alloc((size_t)MAX_SLOTS * 4);
  int*   tki  = (int*)alloc((size_t)NTOK * 2 * 4);
  float* tkw  = (float*)alloc((size_t)NTOK * 2 * 4);
  int*   tslot= (int*)alloc((size_t)NTOK * 2 * 4);
  int*   ctrl = (int*)alloc(8192);

  // dbuf (25600*2048*2 = 104,857,600 B) aliases [Xbf..Wut) (109,051,904 B): all three
  // are dead once k_gateup finishes; k_down/k_combine are dbuf's only users.
  bf16* dbuf = (bf16*)Xbf;

  hipMemsetAsync(ctrl, 0, 8192, stream);

  k_front<<<dim3(TCVT_BLOCKS + NTOK / 4), dim3(256), 0, stream>>>(
      x, Wr, Xbf, tki, tkw, Wg, Wu, Wd, Wg_s, Wu_s, Wd_s, Wgt, Wut, Wdt);
  k_setup<<<dim3(1), dim3(1024), 0, stream>>>(tki, ctrl, stok, sw);
  k_scatter<<<dim3(NTOK / 256), dim3(256), 0, stream>>>(tki, tkw, ctrl, stok, sw, tslot);
  k_gateup<<<dim3(ITR / BN, MAX_SLOTS / BM), dim3(256), 0, stream>>>(Xbf, Wgt, Wut, stok, sw, ctrl, hbuf);
  k_down<<<dim3(HID / BN, MAX_SLOTS / BM), dim3(256), 0, stream>>>(hbuf, Wdt, stok, ctrl, dbuf);
  k_combine<<<dim3(NTOK), dim3(256), 0, stream>>>(dbuf, tslot, ctrl, out);
}